// Round 1
// baseline (501.471 us; speedup 1.0000x reference)
//
#include <hip/hip_runtime.h>
#include <hip/hip_bf16.h>

// ---------------------------------------------------------------------------
// RnnGruModel: MLP (1600->60->15->10) fused with GRU-layer0 input-gate
// precompute, then 3 stacked GRU layers (H=5) + output projection.
// Layouts: X (T,B,F) row-major, row r = t*128 + b.  Output (T,1,B): t*128+b.
// ---------------------------------------------------------------------------

#define T_DIM 256
#define B_DIM 128
#define F_DIM 1600
#define H1_DIM 60
#define H2_DIM 15
#define H3_DIM 10
#define GH 5

__device__ __forceinline__ float fast_tanh(float x) {
    float e = __expf(2.0f * x);
    return 1.0f - __fdividef(2.0f, e + 1.0f);   // safe at +-inf
}
__device__ __forceinline__ float fast_sigmoid(float x) {
    return __fdividef(1.0f, 1.0f + __expf(-x)); // safe at +-inf
}

// ---------------------------------------------------------------------------
// Kernel 1: per-row MLP + gi0 precompute.
// Grid: 512 blocks x 256 threads. Each block: 64 rows (lane = row),
// 4 waves = 4 K-quarters of 400 each, reduced through LDS.
// ---------------------------------------------------------------------------
__global__ __launch_bounds__(256) void mlp_kernel(
    const float* __restrict__ X,
    const float* __restrict__ W1, const float* __restrict__ b1,
    const float* __restrict__ W2, const float* __restrict__ b2,
    const float* __restrict__ W3, const float* __restrict__ b3,
    const float* __restrict__ wih0, const float* __restrict__ bih0,
    float* __restrict__ gi0)
{
    __shared__ float red[3][64][61];   // +1 pad -> conflict-free

    const int tid  = threadIdx.x;
    const int lane = tid & 63;
    const int kq   = __builtin_amdgcn_readfirstlane(tid >> 6);  // wave-uniform SGPR
    const int row  = blockIdx.x * 64 + lane;

    const float* xp = X + (size_t)row * F_DIM + kq * 400;

    float acc[H1_DIM];
#pragma unroll
    for (int o = 0; o < H1_DIM; ++o) acc[o] = 0.0f;

    // double-buffered 8-float chunks of the X row
    float4 a0 = *(const float4*)(xp);
    float4 a1 = *(const float4*)(xp + 4);

    const int kbase0 = kq * 400;
    for (int c = 0; c < 50; ++c) {
        float4 n0 = make_float4(0.f, 0.f, 0.f, 0.f);
        float4 n1 = n0;
        if (c < 49) {
            n0 = *(const float4*)(xp + c * 8 + 8);
            n1 = *(const float4*)(xp + c * 8 + 12);
        }
        const float* wp = W1 + kbase0 + c * 8;   // uniform address -> s_load
#pragma unroll
        for (int o = 0; o < H1_DIM; ++o) {
            const float4 w0 = *(const float4*)(wp + o * F_DIM);
            const float4 w1 = *(const float4*)(wp + o * F_DIM + 4);
            acc[o] += (a0.x * w0.x + a0.y * w0.y) + (a0.z * w0.z + a0.w * w0.w)
                    + (a1.x * w1.x + a1.y * w1.y) + (a1.z * w1.z + a1.w * w1.w);
        }
        a0 = n0; a1 = n1;
    }

    if (kq > 0) {
#pragma unroll
        for (int o = 0; o < H1_DIM; ++o) red[kq - 1][lane][o] = acc[o];
    }
    __syncthreads();
    if (kq != 0) return;

#pragma unroll
    for (int o = 0; o < H1_DIM; ++o)
        acc[o] += red[0][lane][o] + red[1][lane][o] + red[2][lane][o];

    // MLP layer 1 activation
    float h1v[H1_DIM];
#pragma unroll
    for (int o = 0; o < H1_DIM; ++o) h1v[o] = fast_tanh(acc[o] + b1[o]);

    // MLP layer 2
    float h2v[H2_DIM];
#pragma unroll
    for (int j = 0; j < H2_DIM; ++j) {
        float s = b2[j];
#pragma unroll
        for (int o = 0; o < H1_DIM; ++o) s += W2[j * H1_DIM + o] * h1v[o];
        h2v[j] = fast_tanh(s);
    }

    // MLP layer 3 (no activation)
    float h3v[H3_DIM];
#pragma unroll
    for (int m = 0; m < H3_DIM; ++m) {
        float s = b3[m];
#pragma unroll
        for (int j = 0; j < H2_DIM; ++j) s += W3[m * H2_DIM + j] * h2v[j];
        h3v[m] = s;
    }

    // GRU layer-0 input gates: gi0 = h3 @ w_ih0^T + b_ih0  (15 values, pad to 16)
    float gv[15];
#pragma unroll
    for (int q = 0; q < 15; ++q) {
        float s = bih0[q];
#pragma unroll
        for (int m = 0; m < H3_DIM; ++m) s += wih0[q * H3_DIM + m] * h3v[m];
        gv[q] = s;
    }

    float4* dst = (float4*)(gi0 + (size_t)row * 16);
    dst[0] = make_float4(gv[0],  gv[1],  gv[2],  gv[3]);
    dst[1] = make_float4(gv[4],  gv[5],  gv[6],  gv[7]);
    dst[2] = make_float4(gv[8],  gv[9],  gv[10], gv[11]);
    dst[3] = make_float4(gv[12], gv[13], gv[14], 0.0f);
}

// ---------------------------------------------------------------------------
// Kernel 2: 3 stacked GRU layers + output projection.
// Grid: 32 blocks x 64 threads (1 wave). Each 16-lane group = 1 batch elem;
// lane g (0..14) owns gate g. h (5) replicated in registers via shuffles.
// Sequence buffer lives in LDS, layers run in place.
// MODE 0: gi from LDS (precomputed). MODE 1: middle layer. MODE 2: last+proj.
// ---------------------------------------------------------------------------
template <int MODE>
__device__ __forceinline__ void gru_scan(
    float* __restrict__ seqb, int g, int g14,
    const float* __restrict__ wih, const float* __restrict__ bih,
    const float* __restrict__ whh, const float* __restrict__ bhh,
    const float* __restrict__ Wout, const float* __restrict__ boutp,
    float* __restrict__ out, int b)
{
    float wh[GH];
#pragma unroll
    for (int j = 0; j < GH; ++j) wh[j] = whh[g14 * GH + j];
    const float bh = bhh[g14];

    float wi[GH] = {0, 0, 0, 0, 0};
    float bi = 0.0f;
    if (MODE > 0) {
#pragma unroll
        for (int j = 0; j < GH; ++j) wi[j] = wih[g14 * GH + j];
        bi = bih[g14];
    }
    float wo[GH] = {0, 0, 0, 0, 0};
    float bo = 0.0f;
    if (MODE == 2) {
#pragma unroll
        for (int j = 0; j < GH; ++j) wo[j] = Wout[j];
        bo = boutp[0];
    }

    float h0 = 0, h1 = 0, h2 = 0, h3 = 0, h4 = 0, hm = 0;

    float gi_n = 0;
    float x0 = 0, x1 = 0, x2 = 0, x3 = 0, x4 = 0;
    if (MODE == 0) {
        gi_n = seqb[g];
    } else {
        x0 = seqb[0]; x1 = seqb[1]; x2 = seqb[2]; x3 = seqb[3]; x4 = seqb[4];
    }

    for (int t = 0; t < T_DIM; ++t) {
        float gi;
        float nx0 = 0, nx1 = 0, nx2 = 0, nx3 = 0, nx4 = 0;
        if (MODE == 0) {
            gi = gi_n;
            if (t < T_DIM - 1) gi_n = seqb[(t + 1) * 16 + g];   // prefetch
        } else {
            if (t < T_DIM - 1) {                                  // prefetch
                const float* nxt = seqb + (t + 1) * 16;
                nx0 = nxt[0]; nx1 = nxt[1]; nx2 = nxt[2]; nx3 = nxt[3]; nx4 = nxt[4];
            }
            gi = bi + wi[0] * x0 + wi[1] * x1 + wi[2] * x2 + wi[3] * x3 + wi[4] * x4;
        }

        const float gh = bh + wh[0] * h0 + wh[1] * h1 + wh[2] * h2 + wh[3] * h3 + wh[4] * h4;
        const float s  = gi + gh;
        const float sg = fast_sigmoid(s);                  // r (g<5) / z (5..9)
        const float rr = __shfl(sg, (g - 10) & 15, 16);    // r_i for n-lanes
        const float nv = fast_tanh(gi + rr * gh);          // n_i on lanes 10..14
        const float zz = __shfl(sg, (g - 5) & 15, 16);     // z_i for n-lanes
        hm = (1.0f - zz) * nv + zz * hm;                   // h_i on lanes 10..14

        // broadcast new h to all lanes of the group
        h0 = __shfl(hm, 10, 16);
        h1 = __shfl(hm, 11, 16);
        h2 = __shfl(hm, 12, 16);
        h3 = __shfl(hm, 13, 16);
        h4 = __shfl(hm, 14, 16);

        if (MODE < 2) {
            if (g >= 10) seqb[t * 16 + (g - 10)] = hm;     // layer output in place
        } else {
            if (g == 0)
                out[t * B_DIM + b] = bo + wo[0] * h0 + wo[1] * h1 + wo[2] * h2
                                        + wo[3] * h3 + wo[4] * h4;
        }
        if (MODE > 0) { x0 = nx0; x1 = nx1; x2 = nx2; x3 = nx3; x4 = nx4; }
    }
}

__global__ __launch_bounds__(64) void gru_kernel(
    const float* __restrict__ gi0,
    const float* __restrict__ whh0, const float* __restrict__ bhh0,
    const float* __restrict__ wih1, const float* __restrict__ whh1,
    const float* __restrict__ bih1, const float* __restrict__ bhh1,
    const float* __restrict__ wih2, const float* __restrict__ whh2,
    const float* __restrict__ bih2, const float* __restrict__ bhh2,
    const float* __restrict__ Wout, const float* __restrict__ bout,
    float* __restrict__ out)
{
    __shared__ float seq[4][T_DIM][16];     // 64 KB: gi0 staging, then layer seqs

    const int tid = threadIdx.x;
    const int grp = tid >> 4;
    const int g   = tid & 15;
    const int g14 = (g < 15) ? g : 14;
    const int b0  = blockIdx.x * 4;
    const int b   = b0 + grp;

    // stage gi0 for this block's 4 batches into LDS (coalesced float4 copy)
    {
        float4* seq4 = (float4*)seq;
        const float4* src4 = (const float4*)gi0;
        const int c  = tid & 15;        // 16 float4 per timestep (4 rows x 16 floats)
        const int bi = c >> 2;
        const int q  = c & 3;
        for (int it = 0; it < 64; ++it) {
            const int t = it * 4 + (tid >> 4);
            const int r = t * B_DIM + b0 + bi;
            seq4[(bi * T_DIM + t) * 4 + q] = src4[(size_t)r * 4 + q];
        }
    }
    __syncthreads();

    float* seqb = &seq[grp][0][0];

    gru_scan<0>(seqb, g, g14, whh0, bhh0, whh0, bhh0, Wout, bout, out, b);
    gru_scan<1>(seqb, g, g14, wih1, bih1, whh1, bhh1, Wout, bout, out, b);
    gru_scan<2>(seqb, g, g14, wih2, bih2, whh2, bhh2, Wout, bout, out, b);
}

// ---------------------------------------------------------------------------
extern "C" void kernel_launch(void* const* d_in, const int* in_sizes, int n_in,
                              void* d_out, int out_size, void* d_ws, size_t ws_size,
                              hipStream_t stream)
{
    (void)in_sizes; (void)n_in; (void)out_size; (void)ws_size;

    const float* X    = (const float*)d_in[0];
    const float* W1   = (const float*)d_in[1];
    const float* b1   = (const float*)d_in[2];
    const float* W2   = (const float*)d_in[3];
    const float* b2   = (const float*)d_in[4];
    const float* W3   = (const float*)d_in[5];
    const float* b3   = (const float*)d_in[6];
    const float* wih0 = (const float*)d_in[7];
    const float* whh0 = (const float*)d_in[8];
    const float* bih0 = (const float*)d_in[9];
    const float* bhh0 = (const float*)d_in[10];
    const float* wih1 = (const float*)d_in[11];
    const float* whh1 = (const float*)d_in[12];
    const float* bih1 = (const float*)d_in[13];
    const float* bhh1 = (const float*)d_in[14];
    const float* wih2 = (const float*)d_in[15];
    const float* whh2 = (const float*)d_in[16];
    const float* bih2 = (const float*)d_in[17];
    const float* bhh2 = (const float*)d_in[18];
    const float* Wout = (const float*)d_in[19];
    const float* bout = (const float*)d_in[20];

    float* gi0 = (float*)d_ws;          // (32768, 16) fp32 = 2 MB

    mlp_kernel<<<512, 256, 0, stream>>>(X, W1, b1, W2, b2, W3, b3, wih0, bih0, gi0);
    gru_kernel<<<32, 64, 0, stream>>>(gi0, whh0, bhh0,
                                      wih1, whh1, bih1, bhh1,
                                      wih2, whh2, bih2, bhh2,
                                      Wout, bout, (float*)d_out);
}

// Round 2
// 471.948 us; speedup vs baseline: 1.0626x; 1.0626x over previous
//
#include <hip/hip_runtime.h>
#include <hip/hip_bf16.h>

// ---------------------------------------------------------------------------
// RnnGruModel: MLP (1600->60->15->10) fused with GRU-layer0 input-gate
// precompute, then 3 stacked GRU layers (H=5) + output projection.
// Layouts: X (T,B,F) row-major, row r = t*128 + b.  Output (T,1,B): t*128+b.
// ---------------------------------------------------------------------------

#define T_DIM 256
#define B_DIM 128
#define F_DIM 1600
#define H1_DIM 60
#define H2_DIM 15
#define H3_DIM 10
#define GH 5

// MLP kernel tiling
#define KW     400   // K per wave (4 waves split K=1600)
#define CHUNK  40    // K per staged chunk
#define NCHUNK 10    // KW / CHUNK
#define LPAD   65    // LDS row stride (floats), transposed layout -> conflict-free b32
#define OG     10    // outputs per group (W batch = OG*KB floats in SGPRs)
#define NOG    6
#define KB     8     // k per batch (s_load_dwordx8 per output row)
#define NKB    5     // CHUNK / KB

__device__ __forceinline__ float fast_tanh(float x) {
    float e = __expf(2.0f * x);
    return 1.0f - __fdividef(2.0f, e + 1.0f);   // safe at +-inf
}
__device__ __forceinline__ float fast_sigmoid(float x) {
    return __fdividef(1.0f, 1.0f + __expf(-x)); // safe at +-inf
}

// ---------------------------------------------------------------------------
// Kernel 1: per-row MLP + gi0 precompute.
// Grid: 512 blocks x 256 threads. Block owns 64 rows (lane = row);
// wave w owns K-range [w*400, w*400+400), reduced through LDS at the end.
// X staged coalesced global -> registers -> transposed LDS (k*65 + row).
// W1 consumed via wave-uniform scalar loads (SGPR operand of v_fmac).
// ---------------------------------------------------------------------------
__global__ __launch_bounds__(256) void mlp_kernel(
    const float* __restrict__ X,
    const float* __restrict__ W1, const float* __restrict__ b1,
    const float* __restrict__ W2, const float* __restrict__ b2,
    const float* __restrict__ W3, const float* __restrict__ b3,
    const float* __restrict__ wih0, const float* __restrict__ bih0,
    float* __restrict__ gi0)
{
    __shared__ float xs_all[4][CHUNK * LPAD];   // 4 * 2600 * 4B = 41.6 KB

    const int tid  = threadIdx.x;
    const int lane = tid & 63;
    const int w    = __builtin_amdgcn_readfirstlane(tid >> 6);  // wave-uniform
    const int row0 = blockIdx.x * 64;
    const int k0w  = w * KW;

    float* xs = xs_all[w];

    // Flat staging assignment: float4 index v = lane + 64*i, v in [0,640):
    // row = v/10, k-offset = (v%10)*4. Consecutive lanes -> contiguous global.
    int srow[10], skk[10];
#pragma unroll
    for (int i = 0; i < 10; ++i) {
        const int v = lane + 64 * i;
        srow[i] = v / 10;
        skk[i]  = (v % 10) * 4;
    }

    const float* xbase = X + (size_t)row0 * F_DIM + k0w;

    // prologue: load chunk 0 into registers (coalesced)
    float4 xr4[10];
#pragma unroll
    for (int i = 0; i < 10; ++i)
        xr4[i] = *(const float4*)(xbase + srow[i] * F_DIM + skk[i]);

    float acc[H1_DIM];
#pragma unroll
    for (int o = 0; o < H1_DIM; ++o) acc[o] = 0.0f;

    for (int c = 0; c < NCHUNK; ++c) {
        // regs -> LDS, transposed: element (row, k) at xs[k*LPAD + row]
#pragma unroll
        for (int i = 0; i < 10; ++i) {
            xs[(skk[i] + 0) * LPAD + srow[i]] = xr4[i].x;
            xs[(skk[i] + 1) * LPAD + srow[i]] = xr4[i].y;
            xs[(skk[i] + 2) * LPAD + srow[i]] = xr4[i].z;
            xs[(skk[i] + 3) * LPAD + srow[i]] = xr4[i].w;
        }
        // issue next chunk's global loads (completion overlaps compute below)
        if (c + 1 < NCHUNK) {
            const float* xb2 = xbase + (c + 1) * CHUNK;
#pragma unroll
            for (int i = 0; i < 10; ++i)
                xr4[i] = *(const float4*)(xb2 + srow[i] * F_DIM + skk[i]);
        }

        const int kc = k0w + c * CHUNK;  // uniform
#pragma unroll
        for (int og = 0; og < NOG; ++og) {
#pragma unroll
            for (int kb = 0; kb < NKB; ++kb) {
                // X slice for this k-batch: own row, conflict-free b32 reads
                float xv[KB];
#pragma unroll
                for (int j = 0; j < KB; ++j)
                    xv[j] = xs[(kb * KB + j) * LPAD + lane];
                // W1 slice: wave-uniform -> SGPRs; FMA with SGPR operand
#pragma unroll
                for (int o = 0; o < OG; ++o) {
                    const float* wp = W1 + (og * OG + o) * F_DIM + kc + kb * KB;
#pragma unroll
                    for (int j = 0; j < KB; ++j)
                        acc[og * OG + o] += wp[j] * xv[j];
                }
            }
        }
    }

    // ---------------- cross-wave K reduction (reuse staging LDS) -----------
    __syncthreads();                       // everyone done with their xs
    float* red = (float*)xs_all;           // 2 slots of 64*60 floats (30.7 KB)

    if (w == 1 || w == 2) {
#pragma unroll
        for (int o = 0; o < H1_DIM; ++o)
            red[(w - 1) * 64 * H1_DIM + lane * H1_DIM + o] = acc[o];
    }
    __syncthreads();
    if (w == 0) {
#pragma unroll
        for (int o = 0; o < H1_DIM; ++o)
            acc[o] += red[lane * H1_DIM + o] + red[64 * H1_DIM + lane * H1_DIM + o];
    }
    __syncthreads();                       // wave 0 done reading slot 0
    if (w == 3) {
#pragma unroll
        for (int o = 0; o < H1_DIM; ++o)
            red[lane * H1_DIM + o] = acc[o];
    }
    __syncthreads();
    if (w != 0) return;

#pragma unroll
    for (int o = 0; o < H1_DIM; ++o)
        acc[o] += red[lane * H1_DIM + o];

    // ---------------- MLP tail + gi0 (wave 0 only) -------------------------
    float h1v[H1_DIM];
#pragma unroll
    for (int o = 0; o < H1_DIM; ++o) h1v[o] = fast_tanh(acc[o] + b1[o]);

    float h2v[H2_DIM];
#pragma unroll
    for (int j = 0; j < H2_DIM; ++j) {
        float s = b2[j];
#pragma unroll
        for (int o = 0; o < H1_DIM; ++o) s += W2[j * H1_DIM + o] * h1v[o];
        h2v[j] = fast_tanh(s);
    }

    float h3v[H3_DIM];
#pragma unroll
    for (int m = 0; m < H3_DIM; ++m) {
        float s = b3[m];
#pragma unroll
        for (int j = 0; j < H2_DIM; ++j) s += W3[m * H2_DIM + j] * h2v[j];
        h3v[m] = s;
    }

    float gv[15];
#pragma unroll
    for (int q = 0; q < 15; ++q) {
        float s = bih0[q];
#pragma unroll
        for (int m = 0; m < H3_DIM; ++m) s += wih0[q * H3_DIM + m] * h3v[m];
        gv[q] = s;
    }

    const int row = row0 + lane;
    float4* dst = (float4*)(gi0 + (size_t)row * 16);
    dst[0] = make_float4(gv[0],  gv[1],  gv[2],  gv[3]);
    dst[1] = make_float4(gv[4],  gv[5],  gv[6],  gv[7]);
    dst[2] = make_float4(gv[8],  gv[9],  gv[10], gv[11]);
    dst[3] = make_float4(gv[12], gv[13], gv[14], 0.0f);
}

// ---------------------------------------------------------------------------
// Kernel 2: 3 stacked GRU layers + output projection.
// Grid: 32 blocks x 64 threads (1 wave). Each 16-lane group = 1 batch elem;
// lane g (0..14) owns gate g. h (5) replicated in registers via shuffles.
// Sequence buffer lives in LDS, layers run in place.
// MODE 0: gi from LDS (precomputed). MODE 1: middle layer. MODE 2: last+proj.
// ---------------------------------------------------------------------------
template <int MODE>
__device__ __forceinline__ void gru_scan(
    float* __restrict__ seqb, int g, int g14,
    const float* __restrict__ wih, const float* __restrict__ bih,
    const float* __restrict__ whh, const float* __restrict__ bhh,
    const float* __restrict__ Wout, const float* __restrict__ boutp,
    float* __restrict__ out, int b)
{
    float wh[GH];
#pragma unroll
    for (int j = 0; j < GH; ++j) wh[j] = whh[g14 * GH + j];
    const float bh = bhh[g14];

    float wi[GH] = {0, 0, 0, 0, 0};
    float bi = 0.0f;
    if (MODE > 0) {
#pragma unroll
        for (int j = 0; j < GH; ++j) wi[j] = wih[g14 * GH + j];
        bi = bih[g14];
    }
    float wo[GH] = {0, 0, 0, 0, 0};
    float bo = 0.0f;
    if (MODE == 2) {
#pragma unroll
        for (int j = 0; j < GH; ++j) wo[j] = Wout[j];
        bo = boutp[0];
    }

    float h0 = 0, h1 = 0, h2 = 0, h3 = 0, h4 = 0, hm = 0;

    float gi_n = 0;
    float x0 = 0, x1 = 0, x2 = 0, x3 = 0, x4 = 0;
    if (MODE == 0) {
        gi_n = seqb[g];
    } else {
        x0 = seqb[0]; x1 = seqb[1]; x2 = seqb[2]; x3 = seqb[3]; x4 = seqb[4];
    }

    for (int t = 0; t < T_DIM; ++t) {
        float gi;
        float nx0 = 0, nx1 = 0, nx2 = 0, nx3 = 0, nx4 = 0;
        if (MODE == 0) {
            gi = gi_n;
            if (t < T_DIM - 1) gi_n = seqb[(t + 1) * 16 + g];   // prefetch
        } else {
            if (t < T_DIM - 1) {                                  // prefetch
                const float* nxt = seqb + (t + 1) * 16;
                nx0 = nxt[0]; nx1 = nxt[1]; nx2 = nxt[2]; nx3 = nxt[3]; nx4 = nxt[4];
            }
            gi = bi + wi[0] * x0 + wi[1] * x1 + wi[2] * x2 + wi[3] * x3 + wi[4] * x4;
        }

        const float gh = bh + wh[0] * h0 + wh[1] * h1 + wh[2] * h2 + wh[3] * h3 + wh[4] * h4;
        const float s  = gi + gh;
        const float sg = fast_sigmoid(s);                  // r (g<5) / z (5..9)
        const float rr = __shfl(sg, (g - 10) & 15, 16);    // r_i for n-lanes
        const float nv = fast_tanh(gi + rr * gh);          // n_i on lanes 10..14
        const float zz = __shfl(sg, (g - 5) & 15, 16);     // z_i for n-lanes
        hm = (1.0f - zz) * nv + zz * hm;                   // h_i on lanes 10..14

        // broadcast new h to all lanes of the group
        h0 = __shfl(hm, 10, 16);
        h1 = __shfl(hm, 11, 16);
        h2 = __shfl(hm, 12, 16);
        h3 = __shfl(hm, 13, 16);
        h4 = __shfl(hm, 14, 16);

        if (MODE < 2) {
            if (g >= 10) seqb[t * 16 + (g - 10)] = hm;     // layer output in place
        } else {
            if (g == 0)
                out[t * B_DIM + b] = bo + wo[0] * h0 + wo[1] * h1 + wo[2] * h2
                                        + wo[3] * h3 + wo[4] * h4;
        }
        if (MODE > 0) { x0 = nx0; x1 = nx1; x2 = nx2; x3 = nx3; x4 = nx4; }
    }
}

__global__ __launch_bounds__(64) void gru_kernel(
    const float* __restrict__ gi0,
    const float* __restrict__ whh0, const float* __restrict__ bhh0,
    const float* __restrict__ wih1, const float* __restrict__ whh1,
    const float* __restrict__ bih1, const float* __restrict__ bhh1,
    const float* __restrict__ wih2, const float* __restrict__ whh2,
    const float* __restrict__ bih2, const float* __restrict__ bhh2,
    const float* __restrict__ Wout, const float* __restrict__ bout,
    float* __restrict__ out)
{
    __shared__ float seq[4][T_DIM][16];     // 64 KB: gi0 staging, then layer seqs

    const int tid = threadIdx.x;
    const int grp = tid >> 4;
    const int g   = tid & 15;
    const int g14 = (g < 15) ? g : 14;
    const int b0  = blockIdx.x * 4;
    const int b   = b0 + grp;

    // stage gi0 for this block's 4 batches into LDS (coalesced float4 copy)
    {
        float4* seq4 = (float4*)seq;
        const float4* src4 = (const float4*)gi0;
        const int c  = tid & 15;        // 16 float4 per timestep (4 rows x 16 floats)
        const int bi = c >> 2;
        const int q  = c & 3;
        for (int it = 0; it < 64; ++it) {
            const int t = it * 4 + (tid >> 4);
            const int r = t * B_DIM + b0 + bi;
            seq4[(bi * T_DIM + t) * 4 + q] = src4[(size_t)r * 4 + q];
        }
    }
    __syncthreads();

    float* seqb = &seq[grp][0][0];

    gru_scan<0>(seqb, g, g14, whh0, bhh0, whh0, bhh0, Wout, bout, out, b);
    gru_scan<1>(seqb, g, g14, wih1, bih1, whh1, bhh1, Wout, bout, out, b);
    gru_scan<2>(seqb, g, g14, wih2, bih2, whh2, bhh2, Wout, bout, out, b);
}

// ---------------------------------------------------------------------------
extern "C" void kernel_launch(void* const* d_in, const int* in_sizes, int n_in,
                              void* d_out, int out_size, void* d_ws, size_t ws_size,
                              hipStream_t stream)
{
    (void)in_sizes; (void)n_in; (void)out_size; (void)ws_size;

    const float* X    = (const float*)d_in[0];
    const float* W1   = (const float*)d_in[1];
    const float* b1   = (const float*)d_in[2];
    const float* W2   = (const float*)d_in[3];
    const float* b2   = (const float*)d_in[4];
    const float* W3   = (const float*)d_in[5];
    const float* b3   = (const float*)d_in[6];
    const float* wih0 = (const float*)d_in[7];
    const float* whh0 = (const float*)d_in[8];
    const float* bih0 = (const float*)d_in[9];
    const float* bhh0 = (const float*)d_in[10];
    const float* wih1 = (const float*)d_in[11];
    const float* whh1 = (const float*)d_in[12];
    const float* bih1 = (const float*)d_in[13];
    const float* bhh1 = (const float*)d_in[14];
    const float* wih2 = (const float*)d_in[15];
    const float* whh2 = (const float*)d_in[16];
    const float* bih2 = (const float*)d_in[17];
    const float* bhh2 = (const float*)d_in[18];
    const float* Wout = (const float*)d_in[19];
    const float* bout = (const float*)d_in[20];

    float* gi0 = (float*)d_ws;          // (32768, 16) fp32 = 2 MB

    mlp_kernel<<<512, 256, 0, stream>>>(X, W1, b1, W2, b2, W3, b3, wih0, bih0, gi0);
    gru_kernel<<<32, 64, 0, stream>>>(gi0, whh0, bhh0,
                                      wih1, whh1, bih1, bhh1,
                                      wih2, whh2, bih2, bhh2,
                                      Wout, bout, (float*)d_out);
}

// Round 3
// 221.393 us; speedup vs baseline: 2.2651x; 2.1317x over previous
//
#include <hip/hip_runtime.h>
#include <hip/hip_bf16.h>

// ---------------------------------------------------------------------------
// RnnGruModel: MLP (1600->60->15->10) fused with GRU-layer0 input-gate
// precompute, then 3 stacked GRU layers (H=5) + output projection.
// X@W1^T done in bf16 MFMA with hi/lo split (3 products) -> ~fp32 accuracy.
// Layouts: X (T,B,F) row-major, row r = t*128 + b.  Output (T,1,B): t*128+b.
// ---------------------------------------------------------------------------

#define T_DIM 256
#define B_DIM 128
#define F_DIM 1600
#define H1_DIM 60
#define H2_DIM 15
#define H3_DIM 10
#define GH 5
#define NSTEP 50          // K-steps of 32 (1600/32)

typedef __attribute__((ext_vector_type(8))) short bf16x8;   // MFMA A/B frag (4 VGPRs)
typedef __attribute__((ext_vector_type(4))) float f32x4;    // MFMA C/D frag

__device__ __forceinline__ float fast_tanh(float x) {
    float e = __expf(2.0f * x);
    return 1.0f - __fdividef(2.0f, e + 1.0f);   // safe at +-inf
}
__device__ __forceinline__ float fast_sigmoid(float x) {
    return __fdividef(1.0f, 1.0f + __expf(-x)); // safe at +-inf
}
__device__ __forceinline__ ushort f2bf_rn(float x) {        // round-to-nearest bf16
    uint u = __float_as_uint(x);
    u += 0x7fffu + ((u >> 16) & 1u);
    return (ushort)(u >> 16);
}

// ---------------------------------------------------------------------------
// Kernel 0: pack W1 (60x1600 fp32, zero-padded to 64 rows) into frag-ordered
// bf16 hi/lo pairs. Frag f = s*8 + nf*2 + h (s=K-step, nf=N-frag, h=hi/lo);
// within a frag, lane l holds 8 bf16 of B[k = s*32 + (l>>4)*8 + j][n = nf*16
// + (l&15)] = W1[n][k]. A-frags use the SAME (lane-group, slot)->k map, so
// the product is correct regardless of the HW's internal k permutation.
// ---------------------------------------------------------------------------
__global__ __launch_bounds__(256) void pack_w1_kernel(
    const float* __restrict__ W1, ushort* __restrict__ Wp)
{
    const int s  = blockIdx.x;       // 0..49
    const int t  = threadIdx.x;
    const int nf = t >> 6;
    const int l  = t & 63;
    const int n  = nf * 16 + (l & 15);
    const int g  = l >> 4;

    ushort hi[8], lo[8];
#pragma unroll
    for (int j = 0; j < 8; ++j) {
        const int k = s * 32 + g * 8 + j;
        const float v = (n < H1_DIM) ? W1[n * F_DIM + k] : 0.0f;
        const ushort h = f2bf_rn(v);
        const float hf = __uint_as_float(((uint)h) << 16);
        const float r  = v - hf;                       // exact
        hi[j] = h;
        lo[j] = (ushort)(__float_as_uint(r) >> 16);    // truncate: |err| ~ 2^-17 |v|
    }
    ushort* dst = Wp + ((size_t)(s * 8 + nf * 2)) * 512 + l * 8;
#pragma unroll
    for (int j = 0; j < 8; ++j) dst[j] = hi[j];
#pragma unroll
    for (int j = 0; j < 8; ++j) dst[512 + j] = lo[j];
}

// ---------------------------------------------------------------------------
// Kernel 1: per-row MLP + gi0 precompute, MFMA edition.
// Grid: 512 blocks x 256 threads. Block owns 64 rows (4 M-frags of 16);
// the 4 waves split the 50 K-steps (12/13/12/13) and all compute the same
// 64x64 C-tile; partial C reduced through LDS. fp32 tail on wave 0.
// ---------------------------------------------------------------------------
__global__ __launch_bounds__(256) void mlp_kernel(
    const float* __restrict__ X,
    const ushort* __restrict__ Wp,
    const float* __restrict__ b1,
    const float* __restrict__ W2, const float* __restrict__ b2,
    const float* __restrict__ W3, const float* __restrict__ b3,
    const float* __restrict__ wih0, const float* __restrict__ bih0,
    float* __restrict__ gi0)
{
    __shared__ float red[4 * 4096];   // 64 KB: per-wave 64x64 C partials

    const int tid  = threadIdx.x;
    const int l    = tid & 63;
    const int w    = __builtin_amdgcn_readfirstlane(tid >> 6);
    const int lm   = l & 15;          // A-row / B-col lane index
    const int g    = l >> 4;          // k-slot group
    const int row0 = blockIdx.x * 64;

    f32x4 acc[4][4];
#pragma unroll
    for (int mf = 0; mf < 4; ++mf)
#pragma unroll
        for (int nf = 0; nf < 4; ++nf)
            acc[mf][nf] = (f32x4){0.f, 0.f, 0.f, 0.f};

    const int s0 = (w * NSTEP) >> 2;        // 0,12,25,37
    const int s1 = ((w + 1) * NSTEP) >> 2;  // 12,25,37,50

    for (int s = s0; s < s1; ++s) {
        // B frags: per-lane 16B loads, coalesced, L2-resident (400 KB total)
        bf16x8 bh[4], bl[4];
        const ushort* wp_s = Wp + (size_t)s * 4096 + l * 8;
#pragma unroll
        for (int nf = 0; nf < 4; ++nf) {
            bh[nf] = *(const bf16x8*)(wp_s + (nf * 2 + 0) * 512);
            bl[nf] = *(const bf16x8*)(wp_s + (nf * 2 + 1) * 512);
        }
        // A frags: 8 consecutive fp32 per lane per M-frag, convert to hi/lo
        bf16x8 a_hi[4], a_lo[4];
#pragma unroll
        for (int mf = 0; mf < 4; ++mf) {
            const float* ap = X + (size_t)(row0 + mf * 16 + lm) * F_DIM + s * 32 + g * 8;
            const float4 x0 = *(const float4*)ap;
            const float4 x1 = *(const float4*)(ap + 4);
            const float xs8[8] = {x0.x, x0.y, x0.z, x0.w, x1.x, x1.y, x1.z, x1.w};
            bf16x8 ah, al;
#pragma unroll
            for (int j = 0; j < 8; ++j) {
                const float v = xs8[j];
                const uint  u = __float_as_uint(v);
                const uint uh = (u + 0x7fffu + ((u >> 16) & 1u)) & 0xffff0000u;
                const float hf = __uint_as_float(uh);
                const float r  = v - hf;               // exact
                ah[j] = (short)(uh >> 16);
                al[j] = (short)(__float_as_uint(r) >> 16);
            }
            a_hi[mf] = ah; a_lo[mf] = al;
        }
        // 3-product bf16 emulation of fp32 GEMM
#pragma unroll
        for (int mf = 0; mf < 4; ++mf)
#pragma unroll
            for (int nf = 0; nf < 4; ++nf) {
                f32x4 c = acc[mf][nf];
                c = __builtin_amdgcn_mfma_f32_16x16x32_bf16(a_lo[mf], bh[nf], c, 0, 0, 0);
                c = __builtin_amdgcn_mfma_f32_16x16x32_bf16(a_hi[mf], bl[nf], c, 0, 0, 0);
                c = __builtin_amdgcn_mfma_f32_16x16x32_bf16(a_hi[mf], bh[nf], c, 0, 0, 0);
                acc[mf][nf] = c;
            }
    }

    // -------- per-wave C partials -> LDS (C/D map: col=lane&15, row=(l>>4)*4+q)
    float* myred = red + w * 4096;
#pragma unroll
    for (int mf = 0; mf < 4; ++mf)
#pragma unroll
        for (int nf = 0; nf < 4; ++nf)
#pragma unroll
            for (int q = 0; q < 4; ++q)
                myred[(mf * 16 + g * 4 + q) * 64 + nf * 16 + lm] = acc[mf][nf][q];
    __syncthreads();

    // -------- cross-wave reduce (coalesced, conflict-free), write padded ----
    float rsum[16];
#pragma unroll
    for (int i = 0; i < 16; ++i) {
        const int p = tid + 256 * i;
        rsum[i] = red[p] + red[4096 + p] + red[8192 + p] + red[12288 + p];
    }
    __syncthreads();
    float* redp = red + 8192;              // 64 x 65 padded, fits in regions 2-3
#pragma unroll
    for (int i = 0; i < 16; ++i) {
        const int p = tid + 256 * i;
        redp[(p >> 6) * 65 + (p & 63)] = rsum[i];
    }
    __syncthreads();
    if (w != 0) return;

    // ---------------- MLP tail + gi0 (wave 0, lane = row) ------------------
    float h1v[H1_DIM];
#pragma unroll
    for (int o = 0; o < H1_DIM; ++o)
        h1v[o] = fast_tanh(redp[l * 65 + o] + b1[o]);

    float h2v[H2_DIM];
#pragma unroll
    for (int j = 0; j < H2_DIM; ++j) {
        float sacc = b2[j];
#pragma unroll
        for (int o = 0; o < H1_DIM; ++o) sacc += W2[j * H1_DIM + o] * h1v[o];
        h2v[j] = fast_tanh(sacc);
    }

    float h3v[H3_DIM];
#pragma unroll
    for (int m = 0; m < H3_DIM; ++m) {
        float sacc = b3[m];
#pragma unroll
        for (int j = 0; j < H2_DIM; ++j) sacc += W3[m * H2_DIM + j] * h2v[j];
        h3v[m] = sacc;
    }

    float gv[15];
#pragma unroll
    for (int q = 0; q < 15; ++q) {
        float sacc = bih0[q];
#pragma unroll
        for (int m = 0; m < H3_DIM; ++m) sacc += wih0[q * H3_DIM + m] * h3v[m];
        gv[q] = sacc;
    }

    const int row = row0 + l;
    float4* dst = (float4*)(gi0 + (size_t)row * 16);
    dst[0] = make_float4(gv[0],  gv[1],  gv[2],  gv[3]);
    dst[1] = make_float4(gv[4],  gv[5],  gv[6],  gv[7]);
    dst[2] = make_float4(gv[8],  gv[9],  gv[10], gv[11]);
    dst[3] = make_float4(gv[12], gv[13], gv[14], 0.0f);
}

// ---------------------------------------------------------------------------
// Kernel 2: 3 stacked GRU layers + output projection (unchanged, verified).
// Grid: 32 blocks x 64 threads (1 wave). Each 16-lane group = 1 batch elem;
// lane g (0..14) owns gate g. h (5) replicated in registers via shuffles.
// ---------------------------------------------------------------------------
template <int MODE>
__device__ __forceinline__ void gru_scan(
    float* __restrict__ seqb, int g, int g14,
    const float* __restrict__ wih, const float* __restrict__ bih,
    const float* __restrict__ whh, const float* __restrict__ bhh,
    const float* __restrict__ Wout, const float* __restrict__ boutp,
    float* __restrict__ out, int b)
{
    float wh[GH];
#pragma unroll
    for (int j = 0; j < GH; ++j) wh[j] = whh[g14 * GH + j];
    const float bh = bhh[g14];

    float wi[GH] = {0, 0, 0, 0, 0};
    float bi = 0.0f;
    if (MODE > 0) {
#pragma unroll
        for (int j = 0; j < GH; ++j) wi[j] = wih[g14 * GH + j];
        bi = bih[g14];
    }
    float wo[GH] = {0, 0, 0, 0, 0};
    float bo = 0.0f;
    if (MODE == 2) {
#pragma unroll
        for (int j = 0; j < GH; ++j) wo[j] = Wout[j];
        bo = boutp[0];
    }

    float h0 = 0, h1 = 0, h2 = 0, h3 = 0, h4 = 0, hm = 0;

    float gi_n = 0;
    float x0 = 0, x1 = 0, x2 = 0, x3 = 0, x4 = 0;
    if (MODE == 0) {
        gi_n = seqb[g];
    } else {
        x0 = seqb[0]; x1 = seqb[1]; x2 = seqb[2]; x3 = seqb[3]; x4 = seqb[4];
    }

    for (int t = 0; t < T_DIM; ++t) {
        float gi;
        float nx0 = 0, nx1 = 0, nx2 = 0, nx3 = 0, nx4 = 0;
        if (MODE == 0) {
            gi = gi_n;
            if (t < T_DIM - 1) gi_n = seqb[(t + 1) * 16 + g];   // prefetch
        } else {
            if (t < T_DIM - 1) {                                  // prefetch
                const float* nxt = seqb + (t + 1) * 16;
                nx0 = nxt[0]; nx1 = nxt[1]; nx2 = nxt[2]; nx3 = nxt[3]; nx4 = nxt[4];
            }
            gi = bi + wi[0] * x0 + wi[1] * x1 + wi[2] * x2 + wi[3] * x3 + wi[4] * x4;
        }

        const float gh = bh + wh[0] * h0 + wh[1] * h1 + wh[2] * h2 + wh[3] * h3 + wh[4] * h4;
        const float s  = gi + gh;
        const float sg = fast_sigmoid(s);                  // r (g<5) / z (5..9)
        const float rr = __shfl(sg, (g - 10) & 15, 16);    // r_i for n-lanes
        const float nv = fast_tanh(gi + rr * gh);          // n_i on lanes 10..14
        const float zz = __shfl(sg, (g - 5) & 15, 16);     // z_i for n-lanes
        hm = (1.0f - zz) * nv + zz * hm;                   // h_i on lanes 10..14

        h0 = __shfl(hm, 10, 16);
        h1 = __shfl(hm, 11, 16);
        h2 = __shfl(hm, 12, 16);
        h3 = __shfl(hm, 13, 16);
        h4 = __shfl(hm, 14, 16);

        if (MODE < 2) {
            if (g >= 10) seqb[t * 16 + (g - 10)] = hm;     // layer output in place
        } else {
            if (g == 0)
                out[t * B_DIM + b] = bo + wo[0] * h0 + wo[1] * h1 + wo[2] * h2
                                        + wo[3] * h3 + wo[4] * h4;
        }
        if (MODE > 0) { x0 = nx0; x1 = nx1; x2 = nx2; x3 = nx3; x4 = nx4; }
    }
}

__global__ __launch_bounds__(64) void gru_kernel(
    const float* __restrict__ gi0,
    const float* __restrict__ whh0, const float* __restrict__ bhh0,
    const float* __restrict__ wih1, const float* __restrict__ whh1,
    const float* __restrict__ bih1, const float* __restrict__ bhh1,
    const float* __restrict__ wih2, const float* __restrict__ whh2,
    const float* __restrict__ bih2, const float* __restrict__ bhh2,
    const float* __restrict__ Wout, const float* __restrict__ bout,
    float* __restrict__ out)
{
    __shared__ float seq[4][T_DIM][16];     // 64 KB: gi0 staging, then layer seqs

    const int tid = threadIdx.x;
    const int grp = tid >> 4;
    const int g   = tid & 15;
    const int g14 = (g < 15) ? g : 14;
    const int b0  = blockIdx.x * 4;
    const int b   = b0 + grp;

    {
        float4* seq4 = (float4*)seq;
        const float4* src4 = (const float4*)gi0;
        const int c  = tid & 15;        // 16 float4 per timestep (4 rows x 16 floats)
        const int bi = c >> 2;
        const int q  = c & 3;
        for (int it = 0; it < 64; ++it) {
            const int t = it * 4 + (tid >> 4);
            const int r = t * B_DIM + b0 + bi;
            seq4[(bi * T_DIM + t) * 4 + q] = src4[(size_t)r * 4 + q];
        }
    }
    __syncthreads();

    float* seqb = &seq[grp][0][0];

    gru_scan<0>(seqb, g, g14, whh0, bhh0, whh0, bhh0, Wout, bout, out, b);
    gru_scan<1>(seqb, g, g14, wih1, bih1, whh1, bhh1, Wout, bout, out, b);
    gru_scan<2>(seqb, g, g14, wih2, bih2, whh2, bhh2, Wout, bout, out, b);
}

// ---------------------------------------------------------------------------
extern "C" void kernel_launch(void* const* d_in, const int* in_sizes, int n_in,
                              void* d_out, int out_size, void* d_ws, size_t ws_size,
                              hipStream_t stream)
{
    (void)in_sizes; (void)n_in; (void)out_size; (void)ws_size;

    const float* X    = (const float*)d_in[0];
    const float* W1   = (const float*)d_in[1];
    const float* b1   = (const float*)d_in[2];
    const float* W2   = (const float*)d_in[3];
    const float* b2   = (const float*)d_in[4];
    const float* W3   = (const float*)d_in[5];
    const float* b3   = (const float*)d_in[6];
    const float* wih0 = (const float*)d_in[7];
    const float* whh0 = (const float*)d_in[8];
    const float* bih0 = (const float*)d_in[9];
    const float* bhh0 = (const float*)d_in[10];
    const float* wih1 = (const float*)d_in[11];
    const float* whh1 = (const float*)d_in[12];
    const float* bih1 = (const float*)d_in[13];
    const float* bhh1 = (const float*)d_in[14];
    const float* wih2 = (const float*)d_in[15];
    const float* whh2 = (const float*)d_in[16];
    const float* bih2 = (const float*)d_in[17];
    const float* bhh2 = (const float*)d_in[18];
    const float* Wout = (const float*)d_in[19];
    const float* bout = (const float*)d_in[20];

    ushort* Wp  = (ushort*)d_ws;                       // 400 frags * 1 KB = 400 KB
    float*  gi0 = (float*)((char*)d_ws + 524288);      // (32768, 16) fp32 = 2 MB

    pack_w1_kernel<<<NSTEP, 256, 0, stream>>>(W1, Wp);
    mlp_kernel<<<512, 256, 0, stream>>>(X, Wp, b1, W2, b2, W3, b3, wih0, bih0, gi0);
    gru_kernel<<<32, 64, 0, stream>>>(gi0, whh0, bhh0,
                                      wih1, whh1, bih1, bhh1,
                                      wih2, whh2, bih2, bhh2,
                                      Wout, bout, (float*)d_out);
}